// Round 5
// baseline (12190.911 us; speedup 1.0000x reference)
//
#include <hip/hip_runtime.h>

// Problem constants (match reference setup_inputs)
constexpr int L = 64;
constexpr int P = 32768;          // nodes per level (2^15)
constexpr int N = L * P;          // 2,097,152 nodes
constexpr int E_PER = 262144;     // edges per group
constexpr int NLEVELS = L - 1;    // 63 edge groups; group g has dst in level g+1

constexpr int NBLOCKS = 1024;     // 4 blocks/CU, cooperative co-resident
constexpr int NTHREADS = 256;     // 262144 threads = 1 edge/thread/group
constexpr int TOKEN = 0x5EED0001; // barrier token (robust to ws garbage)

// ws layout (ints); each slot on its own 64B line
constexpr int DONE_OFF  = 0;                     // done[g*16], g<63
constexpr int DONE_INTS = NLEVELS * 16;          // 1008
constexpr int FLAG_OFF  = 1024;                  // flags[b*16]
constexpr int SLOT_OFF  = FLAG_OFF + NBLOCKS * 16;
constexpr int WS_INTS   = SLOT_OFF + NBLOCKS * 16;   // ~132 KB

// ---- LLC-direct (agent-scope relaxed) ops: always coherent at the
// memory-side Infinity Cache, never stale in a per-XCD L2, and crucially
// NO cache-invalidate per op (R3's mistake was acquire-per-poll). ----
__device__ __forceinline__ int llc_ld_i(const int* p) {
    return __hip_atomic_load(p, __ATOMIC_RELAXED, __HIP_MEMORY_SCOPE_AGENT);
}
__device__ __forceinline__ float llc_ld_f(const float* p) {
    return __hip_atomic_load(p, __ATOMIC_RELAXED, __HIP_MEMORY_SCOPE_AGENT);
}
__device__ __forceinline__ void llc_st_i(int* p, int v) {
    __hip_atomic_store(p, v, __ATOMIC_RELAXED, __HIP_MEMORY_SCOPE_AGENT);
}

__global__ void __launch_bounds__(NTHREADS)
pathfinder_kernel(const float* __restrict__ hdr,
                  const int* __restrict__ src,
                  const int* __restrict__ dst,
                  float* __restrict__ out,
                  int* __restrict__ ws) {
    const int tid = blockIdx.x * NTHREADS + threadIdx.x;   // 0..262143
    int* done  = ws + DONE_OFF;   // completion counters, one line each
    int* flags = ws + FLAG_OFF;   // barrier arrival, one line per block
    int* slots = ws + SLOT_OFF;   // barrier release, one line per block

    // ---- phase A: out = hdr (float4 x2), zero done counters ----
    {
        const float4* h4 = (const float4*)hdr;
        float4* o4 = (float4*)out;
        o4[tid]         = h4[tid];
        o4[tid + E_PER] = h4[tid + E_PER];
        if (tid < DONE_INTS) done[tid] = 0;
    }
    // flush dirty init lines from per-XCD L2 to LLC (readers are LLC-direct)
    __builtin_amdgcn_fence(__ATOMIC_RELEASE, "agent");

    // ---- the ONLY grid barrier: token-based, private release lines ----
    __syncthreads();
    if (blockIdx.x == 0) {
        for (int b = threadIdx.x; b < NBLOCKS; b += NTHREADS)
            if (b != 0)
                while (llc_ld_i(&flags[b * 16]) != TOKEN)
                    __builtin_amdgcn_s_sleep(2);
        __syncthreads();                  // all arrivals verified
        for (int b = threadIdx.x; b < NBLOCKS; b += NTHREADS)
            llc_st_i(&slots[b * 16], TOKEN);   // private line per block: no
    } else {                                    // hot-line release contention
        if (threadIdx.x == 0) {
            llc_st_i(&flags[blockIdx.x * 16], TOKEN);
            while (llc_ld_i(&slots[blockIdx.x * 16]) != TOKEN)
                __builtin_amdgcn_s_sleep(2);
        }
        __syncthreads();
    }

    // ---- phase C: barrier-free dataflow over 63 edge groups ----
    // Invariants: levels complete in order; done[j-1]==E_PER  <=>  all level-j
    // node values final at the LLC (each contributor drains vmcnt(0) between
    // its atomicMax and its done-add). F caches the highest level this lane
    // KNOWS is final -> src levels <= F need no poll at all (~(1-1/l) of edges).
    int F = 0;                       // level 0 final after init+barrier
    int s = src[tid];
    int d = dst[tid];
    for (int g = 0; g < NLEVELS; ++g) {
        int sn = 0, dn = 0;
        if (g + 1 < NLEVELS) {       // prefetch next group's edge (overlaps poll)
            sn = src[(size_t)(g + 1) * E_PER + tid];
            dn = dst[(size_t)(g + 1) * E_PER + tid];
        }
        const int j = s >> 15;       // src node's level (P = 2^15)
        if (j > F) {
            const int* dj = &done[(j - 1) * 16];
            if (llc_ld_i(dj) != E_PER) {
                __builtin_amdgcn_s_sleep(8);                 // short first wait
                while (llc_ld_i(dj) != E_PER)
                    __builtin_amdgcn_s_sleep(64);            // ~1.7us backoff:
            }                                                // keeps hot-line
            F = j;                                           // queue shallow
        }
        asm volatile("" ::: "memory");   // no hoisting value load above poll
        const float v = llc_ld_f(&out[s]) + 1.0f;
        // h >= 0 always -> uint-bitpattern atomicMax == float max (at LLC)
        atomicMax((unsigned int*)out + d, __float_as_uint(v));
        asm volatile("s_waitcnt vmcnt(0)" ::: "memory");  // max ACKed at LLC
        // uniform address -> compiler wave-coalesces to 1 atomic/wave (m20)
        atomicAdd(&done[g * 16], 1);
        s = sn; d = dn;
    }
}

// ---- fallback path (ws too small): R2's proven multi-launch version ----
__global__ void __launch_bounds__(256)
init_kernel(const float4* __restrict__ hdr, float4* __restrict__ out) {
    const int i = blockIdx.x * blockDim.x + threadIdx.x;
    out[i] = hdr[i];
}
__global__ void __launch_bounds__(256)
level_kernel(const int* __restrict__ s, const int* __restrict__ d,
             float* __restrict__ out) {
    const int e = blockIdx.x * blockDim.x + threadIdx.x;
    const float v = out[s[e]] + 1.0f;
    atomicMax((unsigned int*)out + d[e], __float_as_uint(v));
}

extern "C" void kernel_launch(void* const* d_in, const int* in_sizes, int n_in,
                              void* d_out, int out_size, void* d_ws, size_t ws_size,
                              hipStream_t stream) {
    const float* hdr = (const float*)d_in[0];
    const int*   src = (const int*)d_in[1];
    const int*   dst = (const int*)d_in[2];
    float*       out = (float*)d_out;
    int*         ws  = (int*)d_ws;

    if (ws_size >= WS_INTS * sizeof(int)) {
        void* args[] = {(void*)&hdr, (void*)&src, (void*)&dst,
                        (void*)&out, (void*)&ws};
        hipLaunchCooperativeKernel((void*)pathfinder_kernel,
                                   dim3(NBLOCKS), dim3(NTHREADS), args, 0, stream);
    } else {
        init_kernel<<<dim3(N / 4 / 256), dim3(256), 0, stream>>>(
            (const float4*)hdr, (float4*)out);
        for (int l = 0; l < NLEVELS; ++l)
            level_kernel<<<dim3(E_PER / 256), dim3(256), 0, stream>>>(
                src + (size_t)l * E_PER, dst + (size_t)l * E_PER, out);
    }
}

// Round 6
// 1004.464 us; speedup vs baseline: 12.1367x; 12.1367x over previous
//
#include <hip/hip_runtime.h>

// Problem constants (match reference setup_inputs)
constexpr int L = 64;
constexpr int P = 32768;          // nodes per level
constexpr int N = L * P;          // 2,097,152 nodes
constexpr int E_PER = 262144;     // edges per group
constexpr int NLEVELS = L - 1;    // 63 edge groups; group g writes level g+1

constexpr int NBLOCKS = 1024;     // 4 blocks/CU, cooperative co-resident
constexpr int NTHREADS = 256;     // 262144 threads = 1 edge/thread/group

// ws: two arrays of per-block PRIVATE 64B lines (no shared hot lines at all)
constexpr int ARR_OFF = 0;                 // arrive[b]  at ws[b*16]
constexpr int REL_OFF = NBLOCKS * 16;      // release[b] at ws[(NBLOCKS+b)*16]
constexpr int WS_INTS = 2 * NBLOCKS * 16;  // 128 KB

// LLC-direct (relaxed agent) ops: coherent at the memory-side Infinity
// Cache, bypass per-XCD L2, and emit NO cache invalidates (R3's poison) and
// NO fences (R4's poison). Protocol correctness proven by R5 (absmax 0).
__device__ __forceinline__ int llc_ld(const int* p) {
    return __hip_atomic_load(p, __ATOMIC_RELAXED, __HIP_MEMORY_SCOPE_AGENT);
}
__device__ __forceinline__ void llc_st(int* p, int v) {
    __hip_atomic_store(p, v, __ATOMIC_RELAXED, __HIP_MEMORY_SCOPE_AGENT);
}
__device__ __forceinline__ float llc_ld_f(const float* p) {
    return __hip_atomic_load(p, __ATOMIC_RELAXED, __HIP_MEMORY_SCOPE_AGENT);
}

// Grid barrier, generation-numbered (monotone 1..64; ws poison 0xAA.. reads
// as negative int so "< gen" spins safely before first real store).
//  - __syncthreads() at arrival emits s_waitcnt vmcnt(0): the block's
//    atomicMax ops are ACKed at the LLC before its arrival flag lands.
//  - every flag line has exactly 1 writer and 1 polling reader.
__device__ __forceinline__ void grid_barrier(int gen, int* arrive, int* release) {
    __syncthreads();                                   // drain vmem (atomics @ LLC)
    if (blockIdx.x == 0) {
        for (int b = 1 + (int)threadIdx.x; b < NBLOCKS; b += NTHREADS)
            while (llc_ld(&arrive[b * 16]) < gen)      // 4 private lines/thread
                __builtin_amdgcn_s_sleep(2);
        __syncthreads();                               // all arrivals verified
        for (int b = (int)threadIdx.x; b < NBLOCKS; b += NTHREADS)
            llc_st(&release[b * 16], gen);             // private line per block
        __syncthreads();
    } else {
        if (threadIdx.x == 0) {
            llc_st(&arrive[blockIdx.x * 16], gen);
            while (llc_ld(&release[blockIdx.x * 16]) < gen)
                __builtin_amdgcn_s_sleep(2);
        }
        __syncthreads();
    }
    asm volatile("" ::: "memory");                     // no hoisting across
}

__global__ void __launch_bounds__(NTHREADS)
pathfinder_kernel(const float* __restrict__ hdr,
                  const int* __restrict__ src,
                  const int* __restrict__ dst,
                  float* __restrict__ out,
                  int* __restrict__ ws) {
    const int tid = blockIdx.x * NTHREADS + threadIdx.x;   // 0..262143
    int* arrive  = ws + ARR_OFF;
    int* release = ws + REL_OFF;

    // ---- init: out = hdr (float4 x2/thread, normal stores) ----
    {
        const float4* h4 = (const float4*)hdr;
        float4* o4 = (float4*)out;
        o4[tid]         = h4[tid];
        o4[tid + E_PER] = h4[tid + E_PER];
    }
    // flush this block's dirty init lines from its XCD L2 to the LLC
    // (readers are LLC-direct). Each block flushes its own stores; emits
    // wbl2 + waitcnt ONCE per wave for the whole run.
    __builtin_amdgcn_fence(__ATOMIC_RELEASE, "agent");

    // level-0 edge prefetched into registers (immutable data, normal loads)
    int s = src[tid];
    int d = dst[tid];

    grid_barrier(1, arrive, release);                  // init visible

    // ---- 63 sequential groups, 1 edge/thread, zero fences in loop ----
    for (int g = 0; g < NLEVELS; ++g) {
        int sn = 0, dn = 0;
        if (g + 1 < NLEVELS) {                         // prefetch next group's
            sn = src[(size_t)(g + 1) * E_PER + tid];   // edge (overlaps barrier)
            dn = dst[(size_t)(g + 1) * E_PER + tid];
        }
        // gather: LLC-direct -> always fresh (contributors drained before
        // the barrier released us); h >= 0 -> uint atomicMax == float max
        const float v = llc_ld_f(&out[s]) + 1.0f;
        atomicMax((unsigned int*)out + d, __float_as_uint(v));

        if (g + 1 < NLEVELS) grid_barrier(g + 2, arrive, release);
        s = sn; d = dn;
        // last group: kernel-end release handles final visibility for host
    }
}

// ---- fallback (ws too small): R2's proven 943us multi-launch version ----
__global__ void __launch_bounds__(256)
init_kernel(const float4* __restrict__ hdr, float4* __restrict__ out) {
    const int i = blockIdx.x * blockDim.x + threadIdx.x;
    out[i] = hdr[i];
}
__global__ void __launch_bounds__(256)
level_kernel(const int* __restrict__ s, const int* __restrict__ d,
             float* __restrict__ out) {
    const int e = blockIdx.x * blockDim.x + threadIdx.x;
    const float v = out[s[e]] + 1.0f;
    atomicMax((unsigned int*)out + d[e], __float_as_uint(v));
}

extern "C" void kernel_launch(void* const* d_in, const int* in_sizes, int n_in,
                              void* d_out, int out_size, void* d_ws, size_t ws_size,
                              hipStream_t stream) {
    const float* hdr = (const float*)d_in[0];
    const int*   src = (const int*)d_in[1];
    const int*   dst = (const int*)d_in[2];
    float*       out = (float*)d_out;
    int*         ws  = (int*)d_ws;

    if (ws_size >= WS_INTS * sizeof(int)) {
        void* args[] = {(void*)&hdr, (void*)&src, (void*)&dst,
                        (void*)&out, (void*)&ws};
        hipLaunchCooperativeKernel((void*)pathfinder_kernel,
                                   dim3(NBLOCKS), dim3(NTHREADS), args, 0, stream);
    } else {
        init_kernel<<<dim3(N / 4 / 256), dim3(256), 0, stream>>>(
            (const float4*)hdr, (float4*)out);
        for (int l = 0; l < NLEVELS; ++l)
            level_kernel<<<dim3(E_PER / 256), dim3(256), 0, stream>>>(
                src + (size_t)l * E_PER, dst + (size_t)l * E_PER, out);
    }
}